// Round 11
// baseline (19.636 us; speedup 1.0000x reference)
//
#include <hip/hip_runtime.h>

#define NTIMES 8
#define NFREQS 64
#define NSRC   512
#define NBL    66
#define KHALF  33
#define C_MPS  299792458.0f

// DPP-based wave64 reduction (VALU-only, no LDS). Full sum lands in lane 63.
template <int CTRL, int ROW_MASK>
__device__ __forceinline__ float dpp_add(float v) {
    const int moved = __builtin_amdgcn_update_dpp(
        0, __builtin_bit_cast(int, v), CTRL, ROW_MASK, 0xf, true);
    return v + __builtin_bit_cast(float, moved);
}
__device__ __forceinline__ float wave_sum_lane63(float v) {
    v = dpp_add<0x111, 0xf>(v); // row_shr:1
    v = dpp_add<0x112, 0xf>(v); // row_shr:2
    v = dpp_add<0x114, 0xf>(v); // row_shr:4
    v = dpp_add<0x118, 0xf>(v); // row_shr:8  -> lane15 of each row = row sum
    v = dpp_add<0x142, 0xa>(v); // row_bcast:15 into rows 1,3
    v = dpp_add<0x143, 0xc>(v); // row_bcast:31 into rows 2,3 -> lane63 = total
    return v;
}

// Pre-kernel: tauc[t][k][s] = -(blvec[k] . svec[t,:,s]) / c
__global__ __launch_bounds__(512) void tau_kernel(
    const float* __restrict__ antpos,  // [12][3]
    const float* __restrict__ svec,    // [8][3][512]
    const int*   __restrict__ bls,     // [66][2]
    float*       __restrict__ tauc)    // [8][66][512]
{
    const int k = blockIdx.x % NBL;
    const int t = blockIdx.x / NBL;
    const int s = threadIdx.x;
    const int a1 = bls[2 * k + 0];
    const int a2 = bls[2 * k + 1];
    const float bx = antpos[3 * a2 + 0] - antpos[3 * a1 + 0];
    const float by = antpos[3 * a2 + 1] - antpos[3 * a1 + 1];
    const float bz = antpos[3 * a2 + 2] - antpos[3 * a1 + 2];
    const float sx = svec[((size_t)t * 3 + 0) * NSRC + s];
    const float sy = svec[((size_t)t * 3 + 1) * NSRC + s];
    const float sz = svec[((size_t)t * 3 + 2) * NSRC + s];
    tauc[((size_t)t * NBL + k) * NSRC + s] =
        (bx * sx + by * sy + bz * sz) * (-1.0f / C_MPS);
}

// Output: Re(vis): [2][2][66][8][64] float32 (135168 elems).
// Block = (t, f, khalf). Phase 1: 16 weight vectors + class table in LDS.
// Phase 2: 8 waves sweep 33 baselines (unrolled); rev = freqs[f] * tauc.
__global__ __launch_bounds__(512) void rime_kernel(
    const float* __restrict__ sky,       // [2][2][64][512]
    const float* __restrict__ beam,      // [2][2][8][64][512]
    const float* __restrict__ freqs,     // [64]
    const int*   __restrict__ ant2model, // [12]
    const int*   __restrict__ bls,       // [66][2]
    const float* __restrict__ tauc,      // [8][66][512]
    float*       __restrict__ out)
{
    __shared__ float wsm[16 * NSRC]; // [c=(m1*2+m2)][pq][s], 32 KB
    __shared__ int   cls[NBL];       // class per baseline

    const int bid = blockIdx.x;
    const int f  = bid & (NFREQS - 1);
    const int t  = (bid >> 6) & (NTIMES - 1);
    const int kh = bid >> 9; // 0 or 1

    const int tid  = threadIdx.x; // 0..511
    const int lane = tid & 63;
    const int wv   = tid >> 6;    // 0..7

    // ---- Phase 1a: class table (threads 0..65) ----
    if (tid < NBL) {
        cls[tid] = ant2model[bls[2 * tid + 0]] * 2 + ant2model[bls[2 * tid + 1]];
    }

    // ---- Phase 1b: thread == source; build 16 weight vectors in LDS ----
    {
        const int s = tid;
        const size_t beam_tf = (size_t)t * NFREQS * NSRC + (size_t)f * NSRC + s;
        float bv[2][2]; // [p][m]
        bv[0][0] = beam[(size_t)0 * NTIMES * NFREQS * NSRC + beam_tf];
        bv[0][1] = beam[(size_t)1 * NTIMES * NFREQS * NSRC + beam_tf];
        bv[1][0] = beam[(size_t)2 * NTIMES * NFREQS * NSRC + beam_tf];
        bv[1][1] = beam[(size_t)3 * NTIMES * NFREQS * NSRC + beam_tf];
        const size_t sky_f = (size_t)f * NSRC + s;
        float skv[4];
        skv[0] = sky[(size_t)0 * NFREQS * NSRC + sky_f];
        skv[1] = sky[(size_t)1 * NFREQS * NSRC + sky_f];
        skv[2] = sky[(size_t)2 * NFREQS * NSRC + sky_f];
        skv[3] = sky[(size_t)3 * NFREQS * NSRC + sky_f];
#pragma unroll
        for (int m1 = 0; m1 < 2; ++m1)
#pragma unroll
            for (int m2 = 0; m2 < 2; ++m2)
#pragma unroll
                for (int pq = 0; pq < 4; ++pq) {
                    const int p = pq >> 1, q = pq & 1;
                    wsm[((m1 * 2 + m2) * 4 + pq) * NSRC + s] =
                        bv[p][m1] * skv[pq] * bv[q][m2];
                }
    }

    const float fv = freqs[f];

    __syncthreads();

    // ---- Phase 2: wave wv handles kk = wv + 8*i, i = 0..4 (unrolled) ----
#pragma unroll
    for (int i = 0; i < 5; ++i) {
        const int kk = wv + 8 * i;
        if (kk < KHALF) {
            const int k = kh * KHALF + kk;
            const int c = cls[k];

            // tau loads: addresses independent of everything else -> hoistable
            const float4* tp4 = (const float4*)(tauc + ((size_t)t * NBL + k) * NSRC);
            float4 tau[2];
            tau[0] = tp4[lane];
            tau[1] = tp4[64 + lane];

            const float4* wp = (const float4*)(wsm + (size_t)c * 4 * NSRC);

            float a00 = 0.f, a01 = 0.f, a10 = 0.f, a11 = 0.f;
#pragma unroll
            for (int it = 0; it < 2; ++it) {
                const int s4 = lane + 64 * it;
                const float4 w00 = wp[s4];          // pq stride = 128 float4
                const float4 w01 = wp[128 + s4];
                const float4 w10 = wp[256 + s4];
                const float4 w11 = wp[384 + s4];

#define RIME_BODY(CX)                                                          \
                {                                                              \
                    const float rev = __builtin_amdgcn_fractf(fv * tau[it].CX);\
                    const float cs  = __builtin_amdgcn_cosf(rev);              \
                    a00 += w00.CX * cs;                                        \
                    a01 += w01.CX * cs;                                        \
                    a10 += w10.CX * cs;                                        \
                    a11 += w11.CX * cs;                                        \
                }
                RIME_BODY(x)
                RIME_BODY(y)
                RIME_BODY(z)
                RIME_BODY(w)
#undef RIME_BODY
            }

            const float s00 = wave_sum_lane63(a00);
            const float s01 = wave_sum_lane63(a01);
            const float s10 = wave_sum_lane63(a10);
            const float s11 = wave_sum_lane63(a11);

            if (lane == 63) {
                const int base = k * (NTIMES * NFREQS) + t * NFREQS + f;
                const int pqs  = NBL * NTIMES * NFREQS; // 33792
                out[base]           = s00;
                out[base + pqs]     = s01;
                out[base + 2 * pqs] = s10;
                out[base + 3 * pqs] = s11;
            }
        }
    }
}

extern "C" void kernel_launch(void* const* d_in, const int* in_sizes, int n_in,
                              void* d_out, int out_size, void* d_ws, size_t ws_size,
                              hipStream_t stream) {
    const float* sky     = (const float*)d_in[0];
    const float* beam    = (const float*)d_in[1];
    const float* antpos  = (const float*)d_in[2];
    const float* svec    = (const float*)d_in[3];
    const float* freqs   = (const float*)d_in[4];
    const int*   ant2mod = (const int*)d_in[5];
    const int*   bls     = (const int*)d_in[6];
    float*       out     = (float*)d_out;
    float*       tauc    = (float*)d_ws; // [8][66][512] = 1.08 MB

    tau_kernel<<<NBL * NTIMES, 512, 0, stream>>>(antpos, svec, bls, tauc);

    const int nblocks = NTIMES * NFREQS * 2; // 1024: (t, f, khalf)
    rime_kernel<<<nblocks, 512, 0, stream>>>(sky, beam, freqs,
                                             ant2mod, bls, tauc, out);
}

// Round 12
// 16.139 us; speedup vs baseline: 1.2167x; 1.2167x over previous
//
#include <hip/hip_runtime.h>

#define NTIMES 8
#define NFREQS 64
#define NSRC   512
#define NBL    66
#define KHALF  33
#define C_MPS  299792458.0f

typedef _Float16 v2h __attribute__((ext_vector_type(2)));

#if defined(__has_builtin)
#if __has_builtin(__builtin_amdgcn_fdot2)
#define HAVE_FDOT2 1
#endif
#endif

__device__ __forceinline__ float dot2acc(unsigned int wbits, v2h cs, float acc) {
    const v2h w = __builtin_bit_cast(v2h, wbits);
#ifdef HAVE_FDOT2
    return __builtin_amdgcn_fdot2(w, cs, acc, false);
#else
    return acc + (float)w[0] * (float)cs[0] + (float)w[1] * (float)cs[1];
#endif
}

// DPP-based wave64 reduction (VALU-only, no LDS). Full sum lands in lane 63.
template <int CTRL, int ROW_MASK>
__device__ __forceinline__ float dpp_add(float v) {
    const int moved = __builtin_amdgcn_update_dpp(
        0, __builtin_bit_cast(int, v), CTRL, ROW_MASK, 0xf, true);
    return v + __builtin_bit_cast(float, moved);
}
__device__ __forceinline__ float wave_sum_lane63(float v) {
    v = dpp_add<0x111, 0xf>(v); // row_shr:1
    v = dpp_add<0x112, 0xf>(v); // row_shr:2
    v = dpp_add<0x114, 0xf>(v); // row_shr:4
    v = dpp_add<0x118, 0xf>(v); // row_shr:8  -> lane15 of each row = row sum
    v = dpp_add<0x142, 0xa>(v); // row_bcast:15 into rows 1,3
    v = dpp_add<0x143, 0xc>(v); // row_bcast:31 into rows 2,3 -> lane63 = total
    return v;
}

// Output: Re(vis): [2][2][66][8][64] float32 (135168 elems).
// Block = (t, f, khalf). Phase 1: 16 f16 weight vectors + baseline metadata in
// LDS. Phase 2: 8 waves sweep 33 baselines (unrolled); lane owns 8 consecutive
// sources; accumulate via v_dot2_f32_f16 on packed f16 weight/cos pairs.
__global__ __launch_bounds__(512) void rime_kernel(
    const float* __restrict__ sky,       // [2][2][64][512]
    const float* __restrict__ beam,      // [2][2][8][64][512]
    const float* __restrict__ antpos,    // [12][3]
    const float* __restrict__ svec,      // [8][3][512]
    const float* __restrict__ freqs,     // [64]
    const int*   __restrict__ ant2model, // [12]
    const int*   __restrict__ bls,       // [66][2]
    float*       __restrict__ out)
{
    __shared__ _Float16 wsm[16 * NSRC] __attribute__((aligned(16))); // 16 KB
    __shared__ float4   btab[NBL]; // (blvec.xyz, bitcast class)

    const int bid = blockIdx.x;
    const int f  = bid & (NFREQS - 1);
    const int t  = (bid >> 6) & (NTIMES - 1);
    const int kh = bid >> 9; // 0 or 1

    const int tid  = threadIdx.x; // 0..511
    const int lane = tid & 63;
    const int wv   = tid >> 6;    // 0..7

    // ---- Phase 1a: baseline metadata table (threads 0..65) ----
    if (tid < NBL) {
        const int a1 = bls[2 * tid + 0];
        const int a2 = bls[2 * tid + 1];
        float4 e;
        e.x = antpos[3 * a2 + 0] - antpos[3 * a1 + 0];
        e.y = antpos[3 * a2 + 1] - antpos[3 * a1 + 1];
        e.z = antpos[3 * a2 + 2] - antpos[3 * a1 + 2];
        e.w = __builtin_bit_cast(float, ant2model[a1] * 2 + ant2model[a2]);
        btab[tid] = e;
    }

    // ---- Phase 1b: thread == source; build 16 f16 weight vectors in LDS ----
    {
        const int s = tid;
        const size_t beam_tf = (size_t)t * NFREQS * NSRC + (size_t)f * NSRC + s;
        float bv[2][2]; // [p][m]
        bv[0][0] = beam[(size_t)0 * NTIMES * NFREQS * NSRC + beam_tf];
        bv[0][1] = beam[(size_t)1 * NTIMES * NFREQS * NSRC + beam_tf];
        bv[1][0] = beam[(size_t)2 * NTIMES * NFREQS * NSRC + beam_tf];
        bv[1][1] = beam[(size_t)3 * NTIMES * NFREQS * NSRC + beam_tf];
        const size_t sky_f = (size_t)f * NSRC + s;
        float skv[4];
        skv[0] = sky[(size_t)0 * NFREQS * NSRC + sky_f];
        skv[1] = sky[(size_t)1 * NFREQS * NSRC + sky_f];
        skv[2] = sky[(size_t)2 * NFREQS * NSRC + sky_f];
        skv[3] = sky[(size_t)3 * NFREQS * NSRC + sky_f];
#pragma unroll
        for (int m1 = 0; m1 < 2; ++m1)
#pragma unroll
            for (int m2 = 0; m2 < 2; ++m2)
#pragma unroll
                for (int pq = 0; pq < 4; ++pq) {
                    const int p = pq >> 1, q = pq & 1;
                    wsm[((m1 * 2 + m2) * 4 + pq) * NSRC + s] =
                        (_Float16)(bv[p][m1] * skv[pq] * bv[q][m2]);
                }
    }

    // per-lane svec registers: lane owns sources 8*lane .. 8*lane+7
    const float4* sv4 = (const float4*)(svec + (size_t)t * 3 * NSRC);
    float sx[8], sy[8], sz[8];
    {
        const float4 ax = sv4[2 * lane], bx4 = sv4[2 * lane + 1];
        const float4 ay = sv4[128 + 2 * lane], by4 = sv4[128 + 2 * lane + 1];
        const float4 az = sv4[256 + 2 * lane], bz4 = sv4[256 + 2 * lane + 1];
        sx[0]=ax.x; sx[1]=ax.y; sx[2]=ax.z; sx[3]=ax.w;
        sx[4]=bx4.x; sx[5]=bx4.y; sx[6]=bx4.z; sx[7]=bx4.w;
        sy[0]=ay.x; sy[1]=ay.y; sy[2]=ay.z; sy[3]=ay.w;
        sy[4]=by4.x; sy[5]=by4.y; sy[6]=by4.z; sy[7]=by4.w;
        sz[0]=az.x; sz[1]=az.y; sz[2]=az.z; sz[3]=az.w;
        sz[4]=bz4.x; sz[5]=bz4.y; sz[6]=bz4.z; sz[7]=bz4.w;
    }

    // phase in REVOLUTIONS for v_cos: rev = (-f/c) * (blvec . svec)
    const float coefrev = -freqs[f] / C_MPS;

    __syncthreads();

    // ---- Phase 2: wave wv handles kk = wv + 8*i, i = 0..4 (unrolled) ----
#pragma unroll
    for (int i = 0; i < 5; ++i) {
        const int kk = wv + 8 * i;
        if (kk < KHALF) {
            const int k = kh * KHALF + kk;
            const float4 m = btab[k];
            const int   c   = __builtin_bit_cast(int, m.w);
            const float bxc = coefrev * m.x;
            const float byc = coefrev * m.y;
            const float bzc = coefrev * m.z;

            // cos for this lane's 8 sources, packed as 4 f16 pairs
            v2h csp[4];
#pragma unroll
            for (int j = 0; j < 4; ++j) {
                const float r0 = __builtin_amdgcn_fractf(
                    bxc * sx[2*j] + byc * sy[2*j] + bzc * sz[2*j]);
                const float r1 = __builtin_amdgcn_fractf(
                    bxc * sx[2*j+1] + byc * sy[2*j+1] + bzc * sz[2*j+1]);
                v2h cp;
                cp[0] = (_Float16)__builtin_amdgcn_cosf(r0);
                cp[1] = (_Float16)__builtin_amdgcn_cosf(r1);
                csp[j] = cp;
            }

            // 4 weight rows of this class, 8 f16 each per lane (one b128 each)
            const uint4* wp = (const uint4*)(wsm + (size_t)(4 * c) * NSRC);
            const uint4 q00 = wp[lane];        // row stride 512 f16 = 64 uint4
            const uint4 q01 = wp[64 + lane];
            const uint4 q10 = wp[128 + lane];
            const uint4 q11 = wp[192 + lane];

            float a00 = 0.f, a01 = 0.f, a10 = 0.f, a11 = 0.f;
            a00 = dot2acc(q00.x, csp[0], a00);
            a01 = dot2acc(q01.x, csp[0], a01);
            a10 = dot2acc(q10.x, csp[0], a10);
            a11 = dot2acc(q11.x, csp[0], a11);
            a00 = dot2acc(q00.y, csp[1], a00);
            a01 = dot2acc(q01.y, csp[1], a01);
            a10 = dot2acc(q10.y, csp[1], a10);
            a11 = dot2acc(q11.y, csp[1], a11);
            a00 = dot2acc(q00.z, csp[2], a00);
            a01 = dot2acc(q01.z, csp[2], a01);
            a10 = dot2acc(q10.z, csp[2], a10);
            a11 = dot2acc(q11.z, csp[2], a11);
            a00 = dot2acc(q00.w, csp[3], a00);
            a01 = dot2acc(q01.w, csp[3], a01);
            a10 = dot2acc(q10.w, csp[3], a10);
            a11 = dot2acc(q11.w, csp[3], a11);

            const float s00 = wave_sum_lane63(a00);
            const float s01 = wave_sum_lane63(a01);
            const float s10 = wave_sum_lane63(a10);
            const float s11 = wave_sum_lane63(a11);

            if (lane == 63) {
                const int base = k * (NTIMES * NFREQS) + t * NFREQS + f;
                const int pqs  = NBL * NTIMES * NFREQS; // 33792
                out[base]           = s00;
                out[base + pqs]     = s01;
                out[base + 2 * pqs] = s10;
                out[base + 3 * pqs] = s11;
            }
        }
    }
}

extern "C" void kernel_launch(void* const* d_in, const int* in_sizes, int n_in,
                              void* d_out, int out_size, void* d_ws, size_t ws_size,
                              hipStream_t stream) {
    const float* sky     = (const float*)d_in[0];
    const float* beam    = (const float*)d_in[1];
    const float* antpos  = (const float*)d_in[2];
    const float* svec    = (const float*)d_in[3];
    const float* freqs   = (const float*)d_in[4];
    const int*   ant2mod = (const int*)d_in[5];
    const int*   bls     = (const int*)d_in[6];
    float*       out     = (float*)d_out;

    const int nblocks = NTIMES * NFREQS * 2; // 1024: (t, f, khalf)
    rime_kernel<<<nblocks, 512, 0, stream>>>(sky, beam, antpos, svec, freqs,
                                             ant2mod, bls, out);
}